// Round 12
// baseline (316.375 us; speedup 1.0000x reference)
//
#include <hip/hip_runtime.h>

typedef int   v4i __attribute__((ext_vector_type(4)));
typedef float v4f __attribute__((ext_vector_type(4)));

#define N_ROWS   262144
#define IN_F     256
#define OUT_F    256
#define N_TILES  (N_ROWS / 16)      // 16384
#define GRID     2048
#define ITERS    (N_TILES / GRID)   // 8

// ---------------- prep: weight int32 -> int8, per-channel offset & scale ----
__global__ void qlin_prep(const int* __restrict__ w,
                          const int* __restrict__ bias,
                          const float* __restrict__ is,
                          const float* __restrict__ wsc,
                          const float* __restrict__ os,
                          const int* __restrict__ izp,
                          signed char* __restrict__ w8,
                          int* __restrict__ off,
                          float* __restrict__ scale) {
    int o = blockIdx.x;
    int k = threadIdx.x;
    int v = w[o * IN_F + k];
    w8[o * IN_F + k] = (signed char)v;
    __shared__ int red[256];
    red[k] = v;
    __syncthreads();
    for (int s = 128; s > 0; s >>= 1) {
        if (k < s) red[k] += red[k + s];
        __syncthreads();
    }
    if (k == 0) {
        off[o]   = bias[o] - izp[0] * red[0];
        scale[o] = is[0] * wsc[o] / os[0];
    }
}

// ---------------- main GEMM -------------------------------------------------
__device__ inline int pack4(v4i a) {
    return (a.x & 255) | ((a.y & 255) << 8) | ((a.z & 255) << 16) | (a.w << 24);
}

#define WAIT_VM(n) asm volatile("s_waitcnt vmcnt(" #n ")" ::: "memory")
#define LGKM0()    asm volatile("s_waitcnt lgkmcnt(0)" ::: "memory")
#define BAR()      __builtin_amdgcn_s_barrier()
#define SB0()      __builtin_amdgcn_sched_barrier(0)

__global__ __launch_bounds__(256, 5) void
qlin_main(const int* __restrict__ x,           // [N][256] int32
          const signed char* __restrict__ w8,  // [256][256] int8
          const int* __restrict__ off,         // [256]
          const float* __restrict__ scale,     // [256]
          const int* __restrict__ ozp,         // [1]
          int* __restrict__ out) {             // [N][256] int32 (int8 values)
    // 2 x 16 KB buffers; the out-transpose reuses the just-consumed x buffer
    __shared__ int xt[2][4096];                // 32 KB total -> 5 blocks/CU

    const int tid  = threadIdx.x;
    const int wid  = tid >> 6;
    const int lane = tid & 63;
    const int l15  = lane & 15;
    const int lg   = lane >> 4;
    const int chBase = wid * 64;

    // ---- persistent weight fragments + per-channel constants ---------------
    v4i Wf[4][4];
#pragma unroll
    for (int cf = 0; cf < 4; ++cf) {
        const signed char* wrow = w8 + (chBase + cf * 16 + l15) * IN_F + lg * 16;
#pragma unroll
        for (int kc = 0; kc < 4; ++kc)
            Wf[cf][kc] = *(const v4i*)(wrow + kc * 64);
    }
    v4i of4[4]; v4f sc4[4];
#pragma unroll
    for (int cf = 0; cf < 4; ++cf) {
        const int cb = chBase + cf * 16 + lg * 4;
        of4[cf] = *(const v4i*)(off + cb);
        sc4[cf] = *(const v4f*)(scale + cb);
    }
    const float ozpf = (float)ozp[0];

    // ---- swizzled x-tile LDS read offsets ----------------------------------
    const int msk = (l15 & 7) << 4;
    int coff[4];
#pragma unroll
    for (int u = 0; u < 4; ++u) coff[u] = (lg * 64 + 16 * u) ^ msk;
    const int rowbase = l15 * 1024;

    const int t0 = blockIdx.x;

    // stage x-tile (16 x 1 KB) into xt[b]; LDS dest linear, XOR swizzle on
    // GLOBAL source (rule #21).
    auto stage = [&](int b, int it) {
        const char* base = (const char*)x + (size_t)(t0 + it * GRID) * (16 * IN_F * 4);
#pragma unroll
        for (int j = 0; j < 4; ++j) {
            const int c = wid * 4 + j;
            const int m = (c & 7) << 4;
            const char* src = base + c * 1024 + ((lane * 16) ^ m);
            __builtin_amdgcn_global_load_lds(
                (const __attribute__((address_space(1))) unsigned int*)src,
                (__attribute__((address_space(3))) unsigned int*)&xt[b][c * 256],
                16, 0, 0);
        }
    };

    v4i res[4];   // epilogue results (per-channel layout)
    v4i d[4];     // transposed rows (per-row layout)

    auto compute = [&](int b) {
        const char* lp = (const char*)xt[b] + rowbase;
        v4i Xf[4];
#pragma unroll
        for (int kc = 0; kc < 4; ++kc) {
            v4i a0 = *(const v4i*)(lp + kc * 256 + coff[0]);
            v4i a1 = *(const v4i*)(lp + kc * 256 + coff[1]);
            v4i a2 = *(const v4i*)(lp + kc * 256 + coff[2]);
            v4i a3 = *(const v4i*)(lp + kc * 256 + coff[3]);
            v4i pk;
            pk.x = pack4(a0); pk.y = pack4(a1); pk.z = pack4(a2); pk.w = pack4(a3);
            Xf[kc] = pk;
        }
        v4i acc[4];
#pragma unroll
        for (int cf = 0; cf < 4; ++cf) acc[cf] = (v4i){0, 0, 0, 0};
#pragma unroll
        for (int kc = 0; kc < 4; ++kc)
#pragma unroll
            for (int cf = 0; cf < 4; ++cf)
                acc[cf] = __builtin_amdgcn_mfma_i32_16x16x64_i8(Wf[cf][kc], Xf[kc], acc[cf], 0, 0, 0);
#pragma unroll
        for (int cf = 0; cf < 4; ++cf) {
#pragma unroll
            for (int r = 0; r < 4; ++r) {
                float v = (float)(acc[cf][r] + of4[cf][r]) * sc4[cf][r] + ozpf;
                v = rintf(v);
                v = fminf(fmaxf(v, -128.0f), 127.0f);
                res[cf][r] = (int)v;
            }
        }
    };

    // write res into xt[b] (dead x data) with per-row XOR swizzle
    auto owrite = [&](int b) {
        const int wm = (l15 & 7) << 4;
#pragma unroll
        for (int cf = 0; cf < 4; ++cf) {
            const int colb = chBase * 4 + lg * 16 + cf * 64;
            *(v4i*)((char*)xt[b] + l15 * 1024 + (colb ^ wm)) = res[cf];
        }
    };

    // read back full rows: wave wid owns rows wid*4..+3; 1 KB per instruction
    auto oread = [&](int b) {
#pragma unroll
        for (int j = 0; j < 4; ++j) {
            const int r = wid * 4 + j;
            const int rm = (r & 7) << 4;
            d[j] = *(const v4i*)((char*)xt[b] + r * 1024 + ((lane * 16) ^ rm));
        }
    };

    // NT stores: one contiguous 1 KB row per instruction -> full 128B lines
    auto ostore = [&](int it) {
        const int rb = (t0 + it * GRID) * 16 + wid * 4;
#pragma unroll
        for (int j = 0; j < 4; ++j)
            __builtin_nontemporal_store(d[j], (v4i*)(out + (rb + j) * OUT_F + lane * 4));
    };

    // ---- pipeline, 4 barriers/iter, ot aliased into consumed x buffer ------
    // B1(top): own DMA retired -> tile visible to all waves.
    // B2: all waves finished reading xt[b] -> owrite may clobber it.
    // B3: all owrites visible -> oread valid.
    // B4: all oreads retired -> stage DMA may overwrite xt[b].
    // VM order/wave: [4 loads][4 stores] per iter (stage before ostore)
    // -> waits {4,8,12,12,12,12,12,8} (in-order retirement op-count).
    stage(0, 0);
    stage(1, 1);

    WAIT_VM(4);  BAR();   // need L0, leave L1
    compute(0);  BAR();
    owrite(0); LGKM0(); BAR();
    oread(0);  LGKM0(); BAR();
    stage(0, 2); SB0();
    ostore(0);

    WAIT_VM(8);  BAR();   // need L1, leave L2,S0
    compute(1);  BAR();
    owrite(1); LGKM0(); BAR();
    oread(1);  LGKM0(); BAR();
    stage(1, 3); SB0();
    ostore(1);

    WAIT_VM(12); BAR();   // need L2, leave S0,L3,S1
    compute(0);  BAR();
    owrite(0); LGKM0(); BAR();
    oread(0);  LGKM0(); BAR();
    stage(0, 4); SB0();
    ostore(2);

    WAIT_VM(12); BAR();   // need L3 (S0 drains), leave S1,L4,S2
    compute(1);  BAR();
    owrite(1); LGKM0(); BAR();
    oread(1);  LGKM0(); BAR();
    stage(1, 5); SB0();
    ostore(3);

    WAIT_VM(12); BAR();   // need L4, leave S2,L5,S3
    compute(0);  BAR();
    owrite(0); LGKM0(); BAR();
    oread(0);  LGKM0(); BAR();
    stage(0, 6); SB0();
    ostore(4);

    WAIT_VM(12); BAR();   // need L5, leave S3,L6,S4
    compute(1);  BAR();
    owrite(1); LGKM0(); BAR();
    oread(1);  LGKM0(); BAR();
    stage(1, 7); SB0();
    ostore(5);

    WAIT_VM(12); BAR();   // need L6, leave S4,L7,S5
    compute(0);  BAR();
    owrite(0); LGKM0(); BAR();
    oread(0);  LGKM0(); BAR();
    ostore(6);

    WAIT_VM(8);  BAR();   // need L7, leave S5,S6
    compute(1);  BAR();
    owrite(1); LGKM0(); BAR();
    oread(1);  LGKM0();
    ostore(7);
}

extern "C" void kernel_launch(void* const* d_in, const int* in_sizes, int n_in,
                              void* d_out, int out_size, void* d_ws, size_t ws_size,
                              hipStream_t stream) {
    const int*   x   = (const int*)d_in[0];
    const int*   w   = (const int*)d_in[1];
    const int*   b   = (const int*)d_in[2];
    const float* is  = (const float*)d_in[3];
    const float* wsc = (const float*)d_in[4];
    const float* os  = (const float*)d_in[5];
    const int*   izp = (const int*)d_in[6];
    const int*   ozp = (const int*)d_in[7];
    int* out = (int*)d_out;

    signed char* w8    = (signed char*)d_ws;                 // 65536 B
    int*         off   = (int*)((char*)d_ws + 65536);        // 1024 B
    float*       scale = (float*)((char*)d_ws + 66560);      // 1024 B

    qlin_prep<<<256, 256, 0, stream>>>(w, b, is, wsc, os, izp, w8, off, scale);
    qlin_main<<<GRID, 256, 0, stream>>>(x, w8, off, scale, ozp, out);
}

// Round 13
// 227.164 us; speedup vs baseline: 1.3927x; 1.3927x over previous
//
#include <hip/hip_runtime.h>

typedef int   v4i __attribute__((ext_vector_type(4)));
typedef float v4f __attribute__((ext_vector_type(4)));

#define N_ROWS   262144
#define IN_F     256
#define OUT_F    256
#define N_TILES  (N_ROWS / 16)      // 16384
#define GRID     2048
#define ITERS    (N_TILES / GRID)   // 8

// ---------------- prep: weight int32 -> int8, per-channel offset & scale ----
__global__ void qlin_prep(const int* __restrict__ w,
                          const int* __restrict__ bias,
                          const float* __restrict__ is,
                          const float* __restrict__ wsc,
                          const float* __restrict__ os,
                          const int* __restrict__ izp,
                          signed char* __restrict__ w8,
                          int* __restrict__ off,
                          float* __restrict__ scale) {
    int o = blockIdx.x;
    int k = threadIdx.x;
    int v = w[o * IN_F + k];
    w8[o * IN_F + k] = (signed char)v;
    __shared__ int red[256];
    red[k] = v;
    __syncthreads();
    for (int s = 128; s > 0; s >>= 1) {
        if (k < s) red[k] += red[k + s];
        __syncthreads();
    }
    if (k == 0) {
        off[o]   = bias[o] - izp[0] * red[0];
        scale[o] = is[0] * wsc[o] / os[0];
    }
}

// ---------------- main GEMM -------------------------------------------------
__device__ inline int pack4(v4i a) {
    return (a.x & 255) | ((a.y & 255) << 8) | ((a.z & 255) << 16) | (a.w << 24);
}

#define WAIT_VM(n) asm volatile("s_waitcnt vmcnt(" #n ")" ::: "memory")
#define LGKM0()    asm volatile("s_waitcnt lgkmcnt(0)" ::: "memory")
#define BAR()      __builtin_amdgcn_s_barrier()
#define SB0()      __builtin_amdgcn_sched_barrier(0)

__global__ __launch_bounds__(256, 4) void
qlin_main(const int* __restrict__ x,           // [N][256] int32
          const signed char* __restrict__ w8,  // [256][256] int8
          const int* __restrict__ off,         // [256]
          const float* __restrict__ scale,     // [256]
          const int* __restrict__ ozp,         // [1]
          int* __restrict__ out) {             // [N][256] int32 (int8 values)
    // 2 x 16 KB buffers; the out-transpose reuses the just-consumed x buffer
    __shared__ int xt[2][4096];                // 32 KB total -> 4 blocks/CU

    const int tid  = threadIdx.x;
    const int wid  = tid >> 6;
    const int lane = tid & 63;
    const int l15  = lane & 15;
    const int lg   = lane >> 4;
    const int chBase = wid * 64;

    // ---- persistent weight fragments + per-channel constants ---------------
    v4i Wf[4][4];
#pragma unroll
    for (int cf = 0; cf < 4; ++cf) {
        const signed char* wrow = w8 + (chBase + cf * 16 + l15) * IN_F + lg * 16;
#pragma unroll
        for (int kc = 0; kc < 4; ++kc)
            Wf[cf][kc] = *(const v4i*)(wrow + kc * 64);
    }
    v4i of4[4]; v4f sc4[4];
#pragma unroll
    for (int cf = 0; cf < 4; ++cf) {
        const int cb = chBase + cf * 16 + lg * 4;
        of4[cf] = *(const v4i*)(off + cb);
        sc4[cf] = *(const v4f*)(scale + cb);
    }
    const float ozpf = (float)ozp[0];

    // ---- swizzled x-tile LDS read offsets ----------------------------------
    const int msk = (l15 & 7) << 4;
    int coff[4];
#pragma unroll
    for (int u = 0; u < 4; ++u) coff[u] = (lg * 64 + 16 * u) ^ msk;
    const int rowbase = l15 * 1024;

    const int t0 = blockIdx.x;

    // stage x-tile (16 x 1 KB) into xt[b]; LDS dest linear, XOR swizzle on
    // GLOBAL source (rule #21).
    auto stage = [&](int b, int it) {
        const char* base = (const char*)x + (size_t)(t0 + it * GRID) * (16 * IN_F * 4);
#pragma unroll
        for (int j = 0; j < 4; ++j) {
            const int c = wid * 4 + j;
            const int m = (c & 7) << 4;
            const char* src = base + c * 1024 + ((lane * 16) ^ m);
            __builtin_amdgcn_global_load_lds(
                (const __attribute__((address_space(1))) unsigned int*)src,
                (__attribute__((address_space(3))) unsigned int*)&xt[b][c * 256],
                16, 0, 0);
        }
    };

    v4i res[4];   // epilogue results (per-channel layout)
    v4i d[4];     // transposed rows (per-row layout)

    auto compute = [&](int b) {
        const char* lp = (const char*)xt[b] + rowbase;
        v4i Xf[4];
#pragma unroll
        for (int kc = 0; kc < 4; ++kc) {
            v4i a0 = *(const v4i*)(lp + kc * 256 + coff[0]);
            v4i a1 = *(const v4i*)(lp + kc * 256 + coff[1]);
            v4i a2 = *(const v4i*)(lp + kc * 256 + coff[2]);
            v4i a3 = *(const v4i*)(lp + kc * 256 + coff[3]);
            v4i pk;
            pk.x = pack4(a0); pk.y = pack4(a1); pk.z = pack4(a2); pk.w = pack4(a3);
            Xf[kc] = pk;
        }
        v4i acc[4];
#pragma unroll
        for (int cf = 0; cf < 4; ++cf) acc[cf] = (v4i){0, 0, 0, 0};
#pragma unroll
        for (int kc = 0; kc < 4; ++kc)
#pragma unroll
            for (int cf = 0; cf < 4; ++cf)
                acc[cf] = __builtin_amdgcn_mfma_i32_16x16x64_i8(Wf[cf][kc], Xf[kc], acc[cf], 0, 0, 0);
#pragma unroll
        for (int cf = 0; cf < 4; ++cf) {
#pragma unroll
            for (int r = 0; r < 4; ++r) {
                float v = (float)(acc[cf][r] + of4[cf][r]) * sc4[cf][r] + ozpf;
                v = rintf(v);
                v = fminf(fmaxf(v, -128.0f), 127.0f);
                res[cf][r] = (int)v;
            }
        }
    };

    // write res into xt[b] (dead x data) with per-row XOR swizzle
    auto owrite = [&](int b) {
        const int wm = (l15 & 7) << 4;
#pragma unroll
        for (int cf = 0; cf < 4; ++cf) {
            const int colb = chBase * 4 + lg * 16 + cf * 64;
            *(v4i*)((char*)xt[b] + l15 * 1024 + (colb ^ wm)) = res[cf];
        }
    };

    // read back full rows: wave wid owns rows wid*4..+3; 1 KB per instruction
    auto oread = [&](int b) {
#pragma unroll
        for (int j = 0; j < 4; ++j) {
            const int r = wid * 4 + j;
            const int rm = (r & 7) << 4;
            d[j] = *(const v4i*)((char*)xt[b] + r * 1024 + ((lane * 16) ^ rm));
        }
    };

    // NT stores: one contiguous 1 KB row per instruction -> full 128B lines
    auto ostore = [&](int it) {
        const int rb = (t0 + it * GRID) * 16 + wid * 4;
#pragma unroll
        for (int j = 0; j < 4; ++j)
            __builtin_nontemporal_store(d[j], (v4i*)(out + (rb + j) * OUT_F + lane * 4));
    };

    // ---- pipeline, 4 barriers/iter, ot aliased into consumed x buffer ------
    // B1(top): own DMA retired -> tile visible to all waves.
    // B2: all waves finished reading xt[b] -> owrite may clobber it.
    // B3: all owrites visible -> oread valid.
    // B4: all oreads retired -> stage DMA may overwrite xt[b].
    // VM order/wave: [4 loads][4 stores] per iter (stage before ostore)
    // -> waits {4,8,12,12,12,12,12,8} (in-order retirement op-count).
    stage(0, 0);
    stage(1, 1);

    WAIT_VM(4);  BAR();   // need L0, leave L1
    compute(0);  BAR();
    owrite(0); LGKM0(); BAR();
    oread(0);  LGKM0(); BAR();
    stage(0, 2); SB0();
    ostore(0);

    WAIT_VM(8);  BAR();   // need L1, leave L2,S0
    compute(1);  BAR();
    owrite(1); LGKM0(); BAR();
    oread(1);  LGKM0(); BAR();
    stage(1, 3); SB0();
    ostore(1);

    WAIT_VM(12); BAR();   // need L2, leave S0,L3,S1
    compute(0);  BAR();
    owrite(0); LGKM0(); BAR();
    oread(0);  LGKM0(); BAR();
    stage(0, 4); SB0();
    ostore(2);

    WAIT_VM(12); BAR();   // need L3 (S0 drains), leave S1,L4,S2
    compute(1);  BAR();
    owrite(1); LGKM0(); BAR();
    oread(1);  LGKM0(); BAR();
    stage(1, 5); SB0();
    ostore(3);

    WAIT_VM(12); BAR();   // need L4, leave S2,L5,S3
    compute(0);  BAR();
    owrite(0); LGKM0(); BAR();
    oread(0);  LGKM0(); BAR();
    stage(0, 6); SB0();
    ostore(4);

    WAIT_VM(12); BAR();   // need L5, leave S3,L6,S4
    compute(1);  BAR();
    owrite(1); LGKM0(); BAR();
    oread(1);  LGKM0(); BAR();
    stage(1, 7); SB0();
    ostore(5);

    WAIT_VM(12); BAR();   // need L6, leave S4,L7,S5
    compute(0);  BAR();
    owrite(0); LGKM0(); BAR();
    oread(0);  LGKM0(); BAR();
    ostore(6);

    WAIT_VM(8);  BAR();   // need L7, leave S5,S6
    compute(1);  BAR();
    owrite(1); LGKM0(); BAR();
    oread(1);  LGKM0();
    ostore(7);
}

extern "C" void kernel_launch(void* const* d_in, const int* in_sizes, int n_in,
                              void* d_out, int out_size, void* d_ws, size_t ws_size,
                              hipStream_t stream) {
    const int*   x   = (const int*)d_in[0];
    const int*   w   = (const int*)d_in[1];
    const int*   b   = (const int*)d_in[2];
    const float* is  = (const float*)d_in[3];
    const float* wsc = (const float*)d_in[4];
    const float* os  = (const float*)d_in[5];
    const int*   izp = (const int*)d_in[6];
    const int*   ozp = (const int*)d_in[7];
    int* out = (int*)d_out;

    signed char* w8    = (signed char*)d_ws;                 // 65536 B
    int*         off   = (int*)((char*)d_ws + 65536);        // 1024 B
    float*       scale = (float*)((char*)d_ws + 66560);      // 1024 B

    qlin_prep<<<256, 256, 0, stream>>>(w, b, is, wsc, os, izp, w8, off, scale);
    qlin_main<<<GRID, 256, 0, stream>>>(x, w8, off, scale, ozp, out);
}

// Round 14
// 94.751 us; speedup vs baseline: 3.3390x; 2.3975x over previous
//
#include <hip/hip_runtime.h>

typedef int   v4i __attribute__((ext_vector_type(4)));
typedef float v4f __attribute__((ext_vector_type(4)));

#define N_ROWS   262144
#define IN_F     256
#define OUT_F    256
#define N_TILES  (N_ROWS / 16)      // 16384
#define GRID     2048
#define ITERS    (N_TILES / GRID)   // 8

// ---------------- prep: weight int32 -> int8, per-channel offset & scale ----
__global__ void qlin_prep(const int* __restrict__ w,
                          const int* __restrict__ bias,
                          const float* __restrict__ is,
                          const float* __restrict__ wsc,
                          const float* __restrict__ os,
                          const int* __restrict__ izp,
                          signed char* __restrict__ w8,
                          int* __restrict__ off,
                          float* __restrict__ scale) {
    int o = blockIdx.x;
    int k = threadIdx.x;
    int v = w[o * IN_F + k];
    w8[o * IN_F + k] = (signed char)v;
    __shared__ int red[256];
    red[k] = v;
    __syncthreads();
    for (int s = 128; s > 0; s >>= 1) {
        if (k < s) red[k] += red[k + s];
        __syncthreads();
    }
    if (k == 0) {
        off[o]   = bias[o] - izp[0] * red[0];
        scale[o] = is[0] * wsc[o] / os[0];
    }
}

// ---------------- main GEMM -------------------------------------------------
__device__ inline int pack4(v4i a) {
    return (a.x & 255) | ((a.y & 255) << 8) | ((a.z & 255) << 16) | (a.w << 24);
}

#define WAIT_VM(n) asm volatile("s_waitcnt vmcnt(" #n ")" ::: "memory")
#define LGKM0()    asm volatile("s_waitcnt lgkmcnt(0)" ::: "memory")
#define BAR()      __builtin_amdgcn_s_barrier()
#define SB0()      __builtin_amdgcn_sched_barrier(0)

__global__ __launch_bounds__(256, 3) void
qlin_main(const int* __restrict__ x,           // [N][256] int32
          const signed char* __restrict__ w8,  // [256][256] int8
          const int* __restrict__ off,         // [256]
          const float* __restrict__ scale,     // [256]
          const int* __restrict__ ozp,         // [1]
          int* __restrict__ out) {             // [N][256] int32 (int8 values)
    // 2 x 16 KB buffers; the out-transpose reuses the just-consumed x buffer.
    // 32 KB LDS -> LDS allows 5 blocks/CU; 84 VGPR (128-slot) allows 4.
    __shared__ int xt[2][4096];

    const int tid  = threadIdx.x;
    const int wid  = tid >> 6;
    const int lane = tid & 63;
    const int l15  = lane & 15;
    const int lg   = lane >> 4;
    const int chBase = wid * 64;

    // ---- persistent weight fragments + per-channel constants ---------------
    v4i Wf[4][4];
#pragma unroll
    for (int cf = 0; cf < 4; ++cf) {
        const signed char* wrow = w8 + (chBase + cf * 16 + l15) * IN_F + lg * 16;
#pragma unroll
        for (int kc = 0; kc < 4; ++kc)
            Wf[cf][kc] = *(const v4i*)(wrow + kc * 64);
    }
    v4i of4[4]; v4f sc4[4];
#pragma unroll
    for (int cf = 0; cf < 4; ++cf) {
        const int cb = chBase + cf * 16 + lg * 4;
        of4[cf] = *(const v4i*)(off + cb);
        sc4[cf] = *(const v4f*)(scale + cb);
    }
    const float ozpf = (float)ozp[0];

    // ---- swizzled x-tile LDS read offsets ----------------------------------
    const int msk = (l15 & 7) << 4;
    int coff[4];
#pragma unroll
    for (int u = 0; u < 4; ++u) coff[u] = (lg * 64 + 16 * u) ^ msk;
    const int rowbase = l15 * 1024;

    const int t0 = blockIdx.x;

    // stage x-tile (16 x 1 KB) into xt[b]; LDS dest linear, XOR swizzle on
    // GLOBAL source (rule #21).
    auto stage = [&](int b, int it) {
        const char* base = (const char*)x + (size_t)(t0 + it * GRID) * (16 * IN_F * 4);
#pragma unroll
        for (int j = 0; j < 4; ++j) {
            const int c = wid * 4 + j;
            const int m = (c & 7) << 4;
            const char* src = base + c * 1024 + ((lane * 16) ^ m);
            __builtin_amdgcn_global_load_lds(
                (const __attribute__((address_space(1))) unsigned int*)src,
                (__attribute__((address_space(3))) unsigned int*)&xt[b][c * 256],
                16, 0, 0);
        }
    };

    v4i res[4];   // epilogue results (per-channel layout)
    v4i d[4];     // transposed rows (per-row layout)

    auto compute = [&](int b) {
        const char* lp = (const char*)xt[b] + rowbase;
        v4i Xf[4];
#pragma unroll
        for (int kc = 0; kc < 4; ++kc) {
            v4i a0 = *(const v4i*)(lp + kc * 256 + coff[0]);
            v4i a1 = *(const v4i*)(lp + kc * 256 + coff[1]);
            v4i a2 = *(const v4i*)(lp + kc * 256 + coff[2]);
            v4i a3 = *(const v4i*)(lp + kc * 256 + coff[3]);
            v4i pk;
            pk.x = pack4(a0); pk.y = pack4(a1); pk.z = pack4(a2); pk.w = pack4(a3);
            Xf[kc] = pk;
        }
        v4i acc[4];
#pragma unroll
        for (int cf = 0; cf < 4; ++cf) acc[cf] = (v4i){0, 0, 0, 0};
#pragma unroll
        for (int kc = 0; kc < 4; ++kc)
#pragma unroll
            for (int cf = 0; cf < 4; ++cf)
                acc[cf] = __builtin_amdgcn_mfma_i32_16x16x64_i8(Wf[cf][kc], Xf[kc], acc[cf], 0, 0, 0);
#pragma unroll
        for (int cf = 0; cf < 4; ++cf) {
#pragma unroll
            for (int r = 0; r < 4; ++r) {
                float v = (float)(acc[cf][r] + of4[cf][r]) * sc4[cf][r] + ozpf;
                v = rintf(v);
                v = fminf(fmaxf(v, -128.0f), 127.0f);
                res[cf][r] = (int)v;
            }
        }
    };

    // write res into xt[b] (dead x data) with per-row XOR swizzle
    auto owrite = [&](int b) {
        const int wm = (l15 & 7) << 4;
#pragma unroll
        for (int cf = 0; cf < 4; ++cf) {
            const int colb = chBase * 4 + lg * 16 + cf * 64;
            *(v4i*)((char*)xt[b] + l15 * 1024 + (colb ^ wm)) = res[cf];
        }
    };

    // read back full rows: wave wid owns rows wid*4..+3; 1 KB per instruction
    auto oread = [&](int b) {
#pragma unroll
        for (int j = 0; j < 4; ++j) {
            const int r = wid * 4 + j;
            const int rm = (r & 7) << 4;
            d[j] = *(const v4i*)((char*)xt[b] + r * 1024 + ((lane * 16) ^ rm));
        }
    };

    // NT stores: one contiguous 1 KB row per instruction -> full 128B lines
    auto ostore = [&](int it) {
        const int rb = (t0 + it * GRID) * 16 + wid * 4;
#pragma unroll
        for (int j = 0; j < 4; ++j)
            __builtin_nontemporal_store(d[j], (v4i*)(out + (rb + j) * OUT_F + lane * 4));
    };

    // ---- pipeline, 4 barriers/iter, ot aliased into consumed x buffer ------
    // B1(top): own DMA retired -> tile visible to all waves.
    // B2: all waves finished reading xt[b] -> owrite may clobber it.
    // B3: all owrites visible -> oread valid.
    // B4: all oreads retired -> stage DMA may overwrite xt[b].
    // VM order/wave: [4 loads][4 stores] per iter (stage before ostore)
    // -> waits {4,8,12,12,12,12,12,8} (in-order retirement op-count).
    stage(0, 0);
    stage(1, 1);

    WAIT_VM(4);  BAR();   // need L0, leave L1
    compute(0);  BAR();
    owrite(0); LGKM0(); BAR();
    oread(0);  LGKM0(); BAR();
    stage(0, 2); SB0();
    ostore(0);

    WAIT_VM(8);  BAR();   // need L1, leave L2,S0
    compute(1);  BAR();
    owrite(1); LGKM0(); BAR();
    oread(1);  LGKM0(); BAR();
    stage(1, 3); SB0();
    ostore(1);

    WAIT_VM(12); BAR();   // need L2, leave S0,L3,S1
    compute(0);  BAR();
    owrite(0); LGKM0(); BAR();
    oread(0);  LGKM0(); BAR();
    stage(0, 4); SB0();
    ostore(2);

    WAIT_VM(12); BAR();   // need L3 (S0 drains), leave S1,L4,S2
    compute(1);  BAR();
    owrite(1); LGKM0(); BAR();
    oread(1);  LGKM0(); BAR();
    stage(1, 5); SB0();
    ostore(3);

    WAIT_VM(12); BAR();   // need L4, leave S2,L5,S3
    compute(0);  BAR();
    owrite(0); LGKM0(); BAR();
    oread(0);  LGKM0(); BAR();
    stage(0, 6); SB0();
    ostore(4);

    WAIT_VM(12); BAR();   // need L5, leave S3,L6,S4
    compute(1);  BAR();
    owrite(1); LGKM0(); BAR();
    oread(1);  LGKM0(); BAR();
    stage(1, 7); SB0();
    ostore(5);

    WAIT_VM(12); BAR();   // need L6, leave S4,L7,S5
    compute(0);  BAR();
    owrite(0); LGKM0(); BAR();
    oread(0);  LGKM0(); BAR();
    ostore(6);

    WAIT_VM(8);  BAR();   // need L7, leave S5,S6
    compute(1);  BAR();
    owrite(1); LGKM0(); BAR();
    oread(1);  LGKM0();
    ostore(7);
}

extern "C" void kernel_launch(void* const* d_in, const int* in_sizes, int n_in,
                              void* d_out, int out_size, void* d_ws, size_t ws_size,
                              hipStream_t stream) {
    const int*   x   = (const int*)d_in[0];
    const int*   w   = (const int*)d_in[1];
    const int*   b   = (const int*)d_in[2];
    const float* is  = (const float*)d_in[3];
    const float* wsc = (const float*)d_in[4];
    const float* os  = (const float*)d_in[5];
    const int*   izp = (const int*)d_in[6];
    const int*   ozp = (const int*)d_in[7];
    int* out = (int*)d_out;

    signed char* w8    = (signed char*)d_ws;                 // 65536 B
    int*         off   = (int*)((char*)d_ws + 65536);        // 1024 B
    float*       scale = (float*)((char*)d_ws + 66560);      // 1024 B

    qlin_prep<<<256, 256, 0, stream>>>(w, b, is, wsc, os, izp, w8, off, scale);
    qlin_main<<<GRID, 256, 0, stream>>>(x, w8, off, scale, ozp, out);
}

// Round 15
// 89.128 us; speedup vs baseline: 3.5497x; 1.0631x over previous
//
#include <hip/hip_runtime.h>

typedef int   v4i __attribute__((ext_vector_type(4)));
typedef float v4f __attribute__((ext_vector_type(4)));

#define N_ROWS   262144
#define IN_F     256
#define OUT_F    256
#define N_TILES  (N_ROWS / 16)      // 16384
#define GRID     4096
#define ITERS    (N_TILES / GRID)   // 4

// ---------------- prep: weight int32 -> int8, per-channel offset & scale ----
__global__ void qlin_prep(const int* __restrict__ w,
                          const int* __restrict__ bias,
                          const float* __restrict__ is,
                          const float* __restrict__ wsc,
                          const float* __restrict__ os,
                          const int* __restrict__ izp,
                          signed char* __restrict__ w8,
                          int* __restrict__ off,
                          float* __restrict__ scale) {
    int o = blockIdx.x;
    int k = threadIdx.x;
    int v = w[o * IN_F + k];
    w8[o * IN_F + k] = (signed char)v;
    __shared__ int red[256];
    red[k] = v;
    __syncthreads();
    for (int s = 128; s > 0; s >>= 1) {
        if (k < s) red[k] += red[k + s];
        __syncthreads();
    }
    if (k == 0) {
        off[o]   = bias[o] - izp[0] * red[0];
        scale[o] = is[0] * wsc[o] / os[0];
    }
}

// ---------------- main GEMM -------------------------------------------------
__device__ inline int pack4(v4i a) {
    return (a.x & 255) | ((a.y & 255) << 8) | ((a.z & 255) << 16) | (a.w << 24);
}

#define WAIT_VM(n) asm volatile("s_waitcnt vmcnt(" #n ")" ::: "memory")
#define LGKM0()    asm volatile("s_waitcnt lgkmcnt(0)" ::: "memory")
#define BAR()      __builtin_amdgcn_s_barrier()
#define SB0()      __builtin_amdgcn_sched_barrier(0)

__global__ __launch_bounds__(256, 3) void
qlin_main(const int* __restrict__ x,           // [N][256] int32
          const signed char* __restrict__ w8,  // [256][256] int8
          const int* __restrict__ off,         // [256]
          const float* __restrict__ scale,     // [256]
          const int* __restrict__ ozp,         // [1]
          int* __restrict__ out) {             // [N][256] int32 (int8 values)
    __shared__ int xt[2][4096];                // 2 x 16 KB x-tile buffers
    __shared__ int ot[4096];                   // 16 KB out-transpose buffer

    const int tid  = threadIdx.x;
    const int wid  = tid >> 6;
    const int lane = tid & 63;
    const int l15  = lane & 15;
    const int lg   = lane >> 4;
    const int chBase = wid * 64;

    // ---- persistent weight fragments + per-channel constants ---------------
    v4i Wf[4][4];
#pragma unroll
    for (int cf = 0; cf < 4; ++cf) {
        const signed char* wrow = w8 + (chBase + cf * 16 + l15) * IN_F + lg * 16;
#pragma unroll
        for (int kc = 0; kc < 4; ++kc)
            Wf[cf][kc] = *(const v4i*)(wrow + kc * 64);
    }
    v4i of4[4]; v4f sc4[4];
#pragma unroll
    for (int cf = 0; cf < 4; ++cf) {
        const int cb = chBase + cf * 16 + lg * 4;
        of4[cf] = *(const v4i*)(off + cb);
        sc4[cf] = *(const v4f*)(scale + cb);
    }
    const float ozpf = (float)ozp[0];

    // ---- swizzled x-tile LDS read offsets ----------------------------------
    const int msk = (l15 & 7) << 4;
    int coff[4];
#pragma unroll
    for (int u = 0; u < 4; ++u) coff[u] = (lg * 64 + 16 * u) ^ msk;
    const int rowbase = l15 * 1024;

    const int t0 = blockIdx.x;

    // stage x-tile (16 x 1 KB) into xt[b]; LDS dest linear, XOR swizzle on
    // GLOBAL source (rule #21).
    auto stage = [&](int b, int it) {
        const char* base = (const char*)x + (size_t)(t0 + it * GRID) * (16 * IN_F * 4);
#pragma unroll
        for (int j = 0; j < 4; ++j) {
            const int c = wid * 4 + j;
            const int m = (c & 7) << 4;
            const char* src = base + c * 1024 + ((lane * 16) ^ m);
            __builtin_amdgcn_global_load_lds(
                (const __attribute__((address_space(1))) unsigned int*)src,
                (__attribute__((address_space(3))) unsigned int*)&xt[b][c * 256],
                16, 0, 0);
        }
    };

    v4i res[4];   // epilogue results (per-channel layout)
    v4i d[4];     // transposed rows (per-row layout)

    auto compute = [&](int b) {
        const char* lp = (const char*)xt[b] + rowbase;
        v4i Xf[4];
#pragma unroll
        for (int kc = 0; kc < 4; ++kc) {
            v4i a0 = *(const v4i*)(lp + kc * 256 + coff[0]);
            v4i a1 = *(const v4i*)(lp + kc * 256 + coff[1]);
            v4i a2 = *(const v4i*)(lp + kc * 256 + coff[2]);
            v4i a3 = *(const v4i*)(lp + kc * 256 + coff[3]);
            v4i pk;
            pk.x = pack4(a0); pk.y = pack4(a1); pk.z = pack4(a2); pk.w = pack4(a3);
            Xf[kc] = pk;
        }
        v4i acc[4];
#pragma unroll
        for (int cf = 0; cf < 4; ++cf) acc[cf] = (v4i){0, 0, 0, 0};
#pragma unroll
        for (int kc = 0; kc < 4; ++kc)
#pragma unroll
            for (int cf = 0; cf < 4; ++cf)
                acc[cf] = __builtin_amdgcn_mfma_i32_16x16x64_i8(Wf[cf][kc], Xf[kc], acc[cf], 0, 0, 0);
#pragma unroll
        for (int cf = 0; cf < 4; ++cf) {
#pragma unroll
            for (int r = 0; r < 4; ++r) {
                float v = (float)(acc[cf][r] + of4[cf][r]) * sc4[cf][r] + ozpf;
                v = rintf(v);
                v = fminf(fmaxf(v, -128.0f), 127.0f);
                res[cf][r] = (int)v;
            }
        }
    };

    // write res into ot with per-row XOR swizzle (content linear after XOR)
    auto owrite = [&]() {
        const int wm = (l15 & 7) << 4;
#pragma unroll
        for (int cf = 0; cf < 4; ++cf) {
            const int colb = chBase * 4 + lg * 16 + cf * 64;
            *(v4i*)((char*)ot + l15 * 1024 + (colb ^ wm)) = res[cf];
        }
    };

    // read back full rows: wave wid owns rows wid*4..+3; 1 KB per instruction
    auto oread = [&]() {
#pragma unroll
        for (int j = 0; j < 4; ++j) {
            const int r = wid * 4 + j;
            const int rm = (r & 7) << 4;
            d[j] = *(const v4i*)((char*)ot + r * 1024 + ((lane * 16) ^ rm));
        }
    };

    // NT stores: one contiguous 1 KB row per instruction -> full 128B lines
    auto ostore = [&](int it) {
        const int rb = (t0 + it * GRID) * 16 + wid * 4;
#pragma unroll
        for (int j = 0; j < 4; ++j)
            __builtin_nontemporal_store(d[j], (v4i*)(out + (rb + j) * OUT_F + lane * 4));
    };

    // ---- pipeline, 2 barriers/iter, 4 iterations ---------------------------
    // Top BAR: x-tile ready (and separates prev iter's oread from this owrite).
    // Mid BAR: ot fully written AND xt[b] fully consumed by all waves
    //          -> stage(b) may overwrite xt[b]; oread may read ot.
    // VM order/wave: [4 loads][4 stores] per iter (stage before ostore)
    // -> waits {4,8,12,8} (in-order retirement op-count).
    stage(0, 0);
    stage(1, 1);

    WAIT_VM(4);  BAR();   // pending L0,L1 -> need L0, leave L1
    compute(0);
    owrite(); LGKM0(); BAR();
    stage(0, 2); SB0();
    oread();  LGKM0();
    ostore(0);

    WAIT_VM(8);  BAR();   // pending L1,L2,S0 -> need L1, leave L2,S0
    compute(1);
    owrite(); LGKM0(); BAR();
    stage(1, 3); SB0();
    oread();  LGKM0();
    ostore(1);

    WAIT_VM(12); BAR();   // pending L2,S0,L3,S1 -> need L2, leave S0,L3,S1
    compute(0);
    owrite(); LGKM0(); BAR();
    oread();  LGKM0();
    ostore(2);

    WAIT_VM(8);  BAR();   // pending S0,L3,S1,S2 -> need L3 (S0 drains), leave S1,S2
    compute(1);
    owrite(); LGKM0(); BAR();
    oread();  LGKM0();
    ostore(3);
}

extern "C" void kernel_launch(void* const* d_in, const int* in_sizes, int n_in,
                              void* d_out, int out_size, void* d_ws, size_t ws_size,
                              hipStream_t stream) {
    const int*   x   = (const int*)d_in[0];
    const int*   w   = (const int*)d_in[1];
    const int*   b   = (const int*)d_in[2];
    const float* is  = (const float*)d_in[3];
    const float* wsc = (const float*)d_in[4];
    const float* os  = (const float*)d_in[5];
    const int*   izp = (const int*)d_in[6];
    const int*   ozp = (const int*)d_in[7];
    int* out = (int*)d_out;

    signed char* w8    = (signed char*)d_ws;                 // 65536 B
    int*         off   = (int*)((char*)d_ws + 65536);        // 1024 B
    float*       scale = (float*)((char*)d_ws + 66560);      // 1024 B

    qlin_prep<<<256, 256, 0, stream>>>(w, b, is, wsc, os, izp, w8, off, scale);
    qlin_main<<<GRID, 256, 0, stream>>>(x, w8, off, scale, ozp, out);
}